// Round 3
// baseline (5355.743 us; speedup 1.0000x reference)
//
#include <hip/hip_runtime.h>
#include <math.h>

#define B_  8
#define T_  400
#define F_  256
#define D_  64
#define K_  16
#define N_  (T_*F_)        // 102400
#define TILE 256
#define NBLK (N_/TILE)     // 400

// ---------------- workspace layout (floats) ----------------
// 0      means_s 8192
// 8192   var_s   8192
// 16384  pi_s    128
// 16512  pu      8192   (-0.5 / (var+1e-6))
// 24704  pw      8192   (m / (var+1e-6))
// 32896  pc0     128
// 33024  cs      128     \
// 33152  sx      8192     > contiguous, zeroed per iteration
// 41344  sx2     8192    /

__global__ void initk(const float* __restrict__ means_in,
                      float* __restrict__ means_s, float* __restrict__ var_s,
                      float* __restrict__ pi_s) {
    int i = blockIdx.x * 256 + threadIdx.x;
    if (i < B_*K_*D_) { means_s[i] = means_in[i]; var_s[i] = 1.0f; }
    if (i < B_*K_)    pi_s[i] = 1.0f / K_;
}

// one wave per (b,k): derived params
__global__ void prepk(const float* __restrict__ means_s, const float* __restrict__ var_s,
                      const float* __restrict__ pi_s,
                      float* __restrict__ pu, float* __restrict__ pw,
                      float* __restrict__ pc0) {
    int bk = blockIdx.x;          // 0..127
    int d  = threadIdx.x;         // 0..63
    int idx = bk * D_ + d;
    float var = var_s[idx];
    float m   = means_s[idx];
    float inv = 1.0f / (var + 1e-6f);
    pu[idx] = -0.5f * inv;
    pw[idx] = m * inv;
    float r1 = logf(6.283185307179586f * var);   // log(2*pi*var)
    float r2 = m * m * inv;
    #pragma unroll
    for (int off = 32; off > 0; off >>= 1) {
        r1 += __shfl_xor(r1, off);
        r2 += __shfl_xor(r2, off);
    }
    if (d == 0) pc0[bk] = logf(pi_s[bk]) - 0.5f * (r1 + r2);
}

// butterfly: v[k] are partials (this lane covers dims 4g..4g+3); sum across the
// 16 g-lanes while routing so lane g ends holding the full sum for k == g.
__device__ __forceinline__ float butterfly16(const float v[16], int g) {
    float a[8];
    {
        const bool c = (g & 1);
        #pragma unroll
        for (int i = 0; i < 8; ++i) {
            float send = c ? v[2*i]   : v[2*i+1];
            float keep = c ? v[2*i+1] : v[2*i];
            a[i] = keep + __shfl_xor(send, 1);
        }
    }
    float b2[4];
    {
        const bool c = (g & 2);
        #pragma unroll
        for (int i = 0; i < 4; ++i) {
            float send = c ? a[2*i]   : a[2*i+1];
            float keep = c ? a[2*i+1] : a[2*i];
            b2[i] = keep + __shfl_xor(send, 2);
        }
    }
    float d2[2];
    {
        const bool c = (g & 4);
        #pragma unroll
        for (int i = 0; i < 2; ++i) {
            float send = c ? b2[2*i]   : b2[2*i+1];
            float keep = c ? b2[2*i+1] : b2[2*i];
            d2[i] = keep + __shfl_xor(send, 4);
        }
    }
    const bool c = (g & 8);
    float send = c ? d2[0] : d2[1];
    float keep = c ? d2[1] : d2[0];
    return keep + __shfl_xor(send, 8);
}

// fused E-step: coalesced lik -> butterfly -> lane-softmax -> post LDS -> accumulate
__global__ __launch_bounds__(256, 5) void estepk(
        const float* __restrict__ xg,
        const float* __restrict__ pu, const float* __restrict__ pw,
        const float* __restrict__ pc0,
        float* __restrict__ cs, float* __restrict__ sx, float* __restrict__ sx2) {
    __shared__ float w_lds[K_*D_];            // 4 KB
    __shared__ float u_lds[K_*D_];            // 4 KB
    __shared__ float post_lds[TILE * 16];     // 16 KB

    const int t  = threadIdx.x;
    const int b  = blockIdx.y;
    const int n0 = blockIdx.x * TILE;

    for (int i = t; i < K_*D_; i += 256) {
        w_lds[i] = pw[b*K_*D_ + i];
        u_lds[i] = pu[b*K_*D_ + i];
    }

    const int lane = t & 63;
    const int g    = lane & 15;   // dim-group: dims 4g..4g+3 / later k == g
    const int ps   = lane >> 4;   // point phase 0..3
    const int w    = t >> 6;      // wave id 0..3

    const float c0_lane = pc0[b*K_ + g];
    const float4* xq = (const float4*)(xg + ((size_t)b*N_ + n0) * D_);
    const float4* w4 = (const float4*)w_lds;
    const float4* u4 = (const float4*)u_lds;
    __syncthreads();

    // ---- phase A: wave w covers points [w*64, w*64+64), 8 points per sweep ----
    #pragma unroll 2
    for (int s = 0; s < 8; ++s) {
        const int p0 = w*64 + s*8 + ps;
        const int p1 = p0 + 4;
        float4 xv0 = xq[p0*16 + g];
        float4 xv1 = xq[p1*16 + g];
        float4 q0, q1;
        q0.x = xv0.x*xv0.x; q0.y = xv0.y*xv0.y; q0.z = xv0.z*xv0.z; q0.w = xv0.w*xv0.w;
        q1.x = xv1.x*xv1.x; q1.y = xv1.y*xv1.y; q1.z = xv1.z*xv1.z; q1.w = xv1.w*xv1.w;

        float v0[16], v1[16];
        #pragma unroll
        for (int k = 0; k < 16; ++k) {
            const float4 wv = w4[k*16 + g];
            const float4 uv = u4[k*16 + g];
            float r0 = xv0.x*wv.x;       r0 = fmaf(q0.x, uv.x, r0);
            r0 = fmaf(xv0.y, wv.y, r0);  r0 = fmaf(q0.y, uv.y, r0);
            r0 = fmaf(xv0.z, wv.z, r0);  r0 = fmaf(q0.z, uv.z, r0);
            r0 = fmaf(xv0.w, wv.w, r0);  r0 = fmaf(q0.w, uv.w, r0);
            v0[k] = r0;
            float r1 = xv1.x*wv.x;       r1 = fmaf(q1.x, uv.x, r1);
            r1 = fmaf(xv1.y, wv.y, r1);  r1 = fmaf(q1.y, uv.y, r1);
            r1 = fmaf(xv1.z, wv.z, r1);  r1 = fmaf(q1.z, uv.z, r1);
            r1 = fmaf(xv1.w, wv.w, r1);  r1 = fmaf(q1.w, uv.w, r1);
            v1[k] = r1;
        }

        #pragma unroll
        for (int pp = 0; pp < 2; ++pp) {
            float lik = (pp ? butterfly16(v1, g) : butterfly16(v0, g)) + c0_lane;
            // softmax over k == over the 16-lane group
            float mx = lik;
            mx = fmaxf(mx, __shfl_xor(mx, 1));
            mx = fmaxf(mx, __shfl_xor(mx, 2));
            mx = fmaxf(mx, __shfl_xor(mx, 4));
            mx = fmaxf(mx, __shfl_xor(mx, 8));
            float ex = __expf(lik - mx);
            float sm = ex;
            sm += __shfl_xor(sm, 1);
            sm += __shfl_xor(sm, 2);
            sm += __shfl_xor(sm, 4);
            sm += __shfl_xor(sm, 8);
            const int p = pp ? p1 : p0;
            post_lds[p*16 + g] = ex / sm;
        }
    }
    __syncthreads();

    // ---- phase B: wave w -> k in [4w,4w+4); lane = (ps<<4)|g ----
    const int kb = w * 4;
    float sa[4][4], s2a[4][4], ca[4];
    #pragma unroll
    for (int i = 0; i < 4; ++i) {
        ca[i] = 0.f;
        #pragma unroll
        for (int j = 0; j < 4; ++j) { sa[i][j] = 0.f; s2a[i][j] = 0.f; }
    }

    #pragma unroll 4
    for (int n = 0; n < TILE; n += 4) {
        const int p = n + ps;
        float4 xv = xq[p*16 + g];
        float4 pv = *(const float4*)&post_lds[p*16 + kb];
        float xf[4] = {xv.x, xv.y, xv.z, xv.w};
        float pf[4] = {pv.x, pv.y, pv.z, pv.w};
        float qf[4];
        #pragma unroll
        for (int j = 0; j < 4; ++j) qf[j] = xf[j]*xf[j];
        #pragma unroll
        for (int i = 0; i < 4; ++i) {
            ca[i] += pf[i];
            #pragma unroll
            for (int j = 0; j < 4; ++j) {
                sa[i][j]  = fmaf(pf[i], xf[j], sa[i][j]);
                s2a[i][j] = fmaf(pf[i], qf[j], s2a[i][j]);
            }
        }
    }

    #pragma unroll
    for (int m = 16; m <= 32; m <<= 1) {
        #pragma unroll
        for (int i = 0; i < 4; ++i) {
            ca[i] += __shfl_xor(ca[i], m);
            #pragma unroll
            for (int j = 0; j < 4; ++j) {
                sa[i][j]  += __shfl_xor(sa[i][j],  m);
                s2a[i][j] += __shfl_xor(s2a[i][j], m);
            }
        }
    }

    if (lane < 16) {
        #pragma unroll
        for (int i = 0; i < 4; ++i) {
            #pragma unroll
            for (int j = 0; j < 4; ++j) {
                atomicAdd(&sx [((size_t)(b*K_ + kb + i))*D_ + 4*lane + j], sa[i][j]);
                atomicAdd(&sx2[((size_t)(b*K_ + kb + i))*D_ + 4*lane + j], s2a[i][j]);
            }
        }
        if (lane == 0) {
            #pragma unroll
            for (int i = 0; i < 4; ++i) atomicAdd(&cs[b*K_ + kb + i], ca[i]);
        }
    }
}

__global__ void mstepk(float* __restrict__ means_s, float* __restrict__ var_s,
                       float* __restrict__ pi_s,
                       const float* __restrict__ cs, const float* __restrict__ sx,
                       const float* __restrict__ sx2) {
    int idx = blockIdx.x * 256 + threadIdx.x;   // < 8192
    int b = idx >> 10;
    int k = (idx >> 6) & 15;
    int d = idx & 63;
    float csv = cs[b*K_ + k];
    float sum = 0.f;
    #pragma unroll
    for (int j = 0; j < 16; ++j) sum += cs[b*K_ + j];
    float sxv = sx[idx], sx2v = sx2[idx];
    float mean = sxv / (csv + 1e-7f);
    float var  = fmaf(mean*mean, csv, fmaf(-2.0f*mean, sxv, sx2v)) + 1e-6f;
    means_s[idx] = mean;
    var_s[idx]   = var;
    if (d == 0) pi_s[b*K_ + k] = csv / sum;
}

// final lik -> sigmoid(scale*lik + bias) -> out[b][n][k], coalesced b32 stores
__global__ __launch_bounds__(256, 5) void finalk(
        const float* __restrict__ xg,
        const float* __restrict__ pu, const float* __restrict__ pw,
        const float* __restrict__ pc0,
        const float* __restrict__ scale, const float* __restrict__ bias,
        float* __restrict__ out) {
    __shared__ float w_lds[K_*D_];
    __shared__ float u_lds[K_*D_];

    const int t  = threadIdx.x;
    const int b  = blockIdx.y;
    const int n0 = blockIdx.x * TILE;

    for (int i = t; i < K_*D_; i += 256) {
        w_lds[i] = pw[b*K_*D_ + i];
        u_lds[i] = pu[b*K_*D_ + i];
    }

    const int lane = t & 63;
    const int g    = lane & 15;
    const int ps   = lane >> 4;
    const int w    = t >> 6;

    const float c0_lane = pc0[b*K_ + g];
    const float sc = scale[0], bi = bias[0];
    const float4* xq = (const float4*)(xg + ((size_t)b*N_ + n0) * D_);
    const float4* w4 = (const float4*)w_lds;
    const float4* u4 = (const float4*)u_lds;
    float* outb = out + ((size_t)b*N_ + n0) * (size_t)K_;
    __syncthreads();

    #pragma unroll 2
    for (int s = 0; s < 8; ++s) {
        const int p0 = w*64 + s*8 + ps;
        const int p1 = p0 + 4;
        float4 xv0 = xq[p0*16 + g];
        float4 xv1 = xq[p1*16 + g];
        float4 q0, q1;
        q0.x = xv0.x*xv0.x; q0.y = xv0.y*xv0.y; q0.z = xv0.z*xv0.z; q0.w = xv0.w*xv0.w;
        q1.x = xv1.x*xv1.x; q1.y = xv1.y*xv1.y; q1.z = xv1.z*xv1.z; q1.w = xv1.w*xv1.w;

        float v0[16], v1[16];
        #pragma unroll
        for (int k = 0; k < 16; ++k) {
            const float4 wv = w4[k*16 + g];
            const float4 uv = u4[k*16 + g];
            float r0 = xv0.x*wv.x;       r0 = fmaf(q0.x, uv.x, r0);
            r0 = fmaf(xv0.y, wv.y, r0);  r0 = fmaf(q0.y, uv.y, r0);
            r0 = fmaf(xv0.z, wv.z, r0);  r0 = fmaf(q0.z, uv.z, r0);
            r0 = fmaf(xv0.w, wv.w, r0);  r0 = fmaf(q0.w, uv.w, r0);
            v0[k] = r0;
            float r1 = xv1.x*wv.x;       r1 = fmaf(q1.x, uv.x, r1);
            r1 = fmaf(xv1.y, wv.y, r1);  r1 = fmaf(q1.y, uv.y, r1);
            r1 = fmaf(xv1.z, wv.z, r1);  r1 = fmaf(q1.z, uv.z, r1);
            r1 = fmaf(xv1.w, wv.w, r1);  r1 = fmaf(q1.w, uv.w, r1);
            v1[k] = r1;
        }

        float lik0 = butterfly16(v0, g) + c0_lane;
        float lik1 = butterfly16(v1, g) + c0_lane;
        float z0 = fmaf(lik0, sc, bi);
        float z1 = fmaf(lik1, sc, bi);
        outb[(size_t)p0*K_ + g] = 1.0f / (1.0f + __expf(-z0));
        outb[(size_t)p1*K_ + g] = 1.0f / (1.0f + __expf(-z1));
    }
}

extern "C" void kernel_launch(void* const* d_in, const int* in_sizes, int n_in,
                              void* d_out, int out_size, void* d_ws, size_t ws_size,
                              hipStream_t stream) {
    const float* xg       = (const float*)d_in[0];
    const float* means_in = (const float*)d_in[1];
    const float* scale    = (const float*)d_in[2];
    const float* bias     = (const float*)d_in[3];
    float* out = (float*)d_out;

    float* ws      = (float*)d_ws;
    float* means_s = ws + 0;
    float* var_s   = ws + 8192;
    float* pi_s    = ws + 16384;
    float* pu      = ws + 16512;
    float* pw      = ws + 24704;
    float* pc0     = ws + 32896;
    float* cs      = ws + 33024;
    float* sx      = ws + 33152;
    float* sx2     = ws + 41344;

    initk<<<dim3(32), dim3(256), 0, stream>>>(means_in, means_s, var_s, pi_s);

    for (int it = 0; it < 5; ++it) {
        prepk<<<dim3(B_*K_), dim3(64), 0, stream>>>(means_s, var_s, pi_s, pu, pw, pc0);
        hipMemsetAsync(cs, 0, (size_t)(128 + 8192 + 8192) * sizeof(float), stream);
        estepk<<<dim3(NBLK, B_), dim3(256), 0, stream>>>(xg, pu, pw, pc0, cs, sx, sx2);
        mstepk<<<dim3(32), dim3(256), 0, stream>>>(means_s, var_s, pi_s, cs, sx, sx2);
    }
    prepk<<<dim3(B_*K_), dim3(64), 0, stream>>>(means_s, var_s, pi_s, pu, pw, pc0);
    finalk<<<dim3(NBLK, B_), dim3(256), 0, stream>>>(xg, pu, pw, pc0, scale, bias, out);
}